// Round 2
// 323.946 us; speedup vs baseline: 1.0574x; 1.0574x over previous
//
#include <hip/hip_runtime.h>
#include <stdint.h>

// NodeLevelInnerProductDecoder: out[b,v,:,:] = zeropad(Z_b) @ zeropad(Z_b)^T
// B=64 graphs, D=128, MAX_NODES=508, 4 views. fp32 in/out.
//
// R1 (this session): timed region = harness re-poison fill (~208us, fixed) + kernel.
// Kernel was ~134us vs ~54us write floor (264MB @ 5.08 TB/s = fill-measured ceiling).
// Changes vs previous: direct-from-global MFMA fragments (input is 12.5MB, L2/L3
// resident -> staging LDS was pure overhead), 64x128 tiles, LDS only for 33.8KB
// C-repack -> 4 blocks/CU (16 waves/CU, was 8), shuffle prefix-sum for offsets
// (was O(b) serial dependent loads, up to ~6us), nontemporal output stores,
// early-out for all-zero tiles.
// R2: fix compile — __builtin_nontemporal_store needs a clang ext_vector, not
// HIP's uint4 class. Use v4u ext_vector_type(4).

typedef __bf16          v8bf __attribute__((ext_vector_type(8)));
typedef unsigned short  v8us __attribute__((ext_vector_type(8)));
typedef float           v4f  __attribute__((ext_vector_type(4)));
typedef unsigned int    v4u  __attribute__((ext_vector_type(4)));

#define NMAX 508
#define DD   128
#define NV   4
#define LDC  132   // fp32 C-tile row stride (+4 pad: 2-way bank alias max, free per m136)

__device__ __forceinline__ unsigned short f32_to_bf16_rne(float f) {
    unsigned int u = __builtin_bit_cast(unsigned int, f);
    u = (u + 0x7fffu + ((u >> 16) & 1u)) >> 16;
    return (unsigned short)u;
}

__device__ __forceinline__ v8bf cvt8(v4f lo, v4f hi) {
    v8us u;
    u[0] = f32_to_bf16_rne(lo.x); u[1] = f32_to_bf16_rne(lo.y);
    u[2] = f32_to_bf16_rne(lo.z); u[3] = f32_to_bf16_rne(lo.w);
    u[4] = f32_to_bf16_rne(hi.x); u[5] = f32_to_bf16_rne(hi.y);
    u[6] = f32_to_bf16_rne(hi.z); u[7] = f32_to_bf16_rne(hi.w);
    return __builtin_bit_cast(v8bf, u);
}

__global__ __launch_bounds__(256, 4)
void adj_gram_kernel(const float* __restrict__ z,
                     const int*   __restrict__ counts,
                     float*       __restrict__ out)
{
    // 64 x 132 fp32 = 33.8 KB -> LDS allows 4 blocks/CU; launch_bounds caps VGPR<=128
    // so waves allow 4 blocks/CU too (16 waves/CU).
    __shared__ __align__(16) float sC[64 * LDC];

    const int blk = blockIdx.x;
    const int b   = blk >> 5;          // graph 0..63
    const int ti  = (blk >> 2) & 7;    // 64-row tile 0..7
    const int tj  = blk & 3;           // 128-col tile 0..3
    const int i0  = ti * 64;
    const int j0  = tj * 128;

    const int tid  = threadIdx.x;
    const int lane = tid & 63;
    const int wave = tid >> 6;         // 0..3 : 32-col slice of the 128-col tile

    // ---- ragged offsets: wave-parallel prefix sum (B = 64 = wave size) ----
    // counts dtype hedge: int64 little-endian high word of values 256..508 is 0.
    const bool is64 = (counts[1] == 0);
    int cnt = is64 ? counts[2 * lane] : counts[lane];
    int inc = cnt;
    #pragma unroll
    for (int s = 1; s < 64; s <<= 1) {
        int t = __shfl_up(inc, s);
        if (lane >= s) inc += t;
    }
    const int n   = __shfl(cnt, b);
    const int off = __shfl(inc, b) - n;   // exclusive prefix at graph b

    const int nx = wave * 32;
    const int lr = lane & 15;            // A: m-row / B: n-col within 16-tile
    const int lk = (lane >> 4) * 8;      // k sub-offset

    v4f acc[4][2];
    #pragma unroll
    for (int mt = 0; mt < 4; ++mt)
        #pragma unroll
        for (int nt = 0; nt < 2; ++nt) acc[mt][nt] = (v4f)0.0f;

    // ---- MFMA with fragments loaded DIRECT from global (input is L2/L3-resident).
    // Per (mt,ks): 4-lane groups read 128B-contiguous, 16 rows per instruction. ----
    if (i0 < n && j0 < n) {              // all-zero tiles skip compute, still write
        const float* zb = z + (size_t)off * DD;
        #pragma unroll
        for (int ks = 0; ks < 4; ++ks) {
            const int ko = ks * 32 + lk;
            v8bf af[4], bfv[2];
            #pragma unroll
            for (int mt = 0; mt < 4; ++mt) {
                const int r = i0 + mt * 16 + lr;
                v4f lo = (v4f)0.0f, hi = (v4f)0.0f;
                if (r < n) {
                    const float* p = zb + (size_t)r * DD + ko;
                    lo = *(const v4f*)p;
                    hi = *(const v4f*)(p + 4);
                }
                af[mt] = cvt8(lo, hi);
            }
            #pragma unroll
            for (int nt = 0; nt < 2; ++nt) {
                const int r = j0 + nx + nt * 16 + lr;
                v4f lo = (v4f)0.0f, hi = (v4f)0.0f;
                if (r < n) {
                    const float* p = zb + (size_t)r * DD + ko;
                    lo = *(const v4f*)p;
                    hi = *(const v4f*)(p + 4);
                }
                bfv[nt] = cvt8(lo, hi);
            }
            #pragma unroll
            for (int mt = 0; mt < 4; ++mt)
                #pragma unroll
                for (int nt = 0; nt < 2; ++nt)
                    acc[mt][nt] = __builtin_amdgcn_mfma_f32_16x16x32_bf16(
                        af[mt], bfv[nt], acc[mt][nt], 0, 0, 0);
        }
    }

    // ---- repack C (MFMA C layout: col=lane&15, row=(lane>>4)*4+reg) -> row-major ----
    const int crow = (lane >> 4) * 4;
    #pragma unroll
    for (int mt = 0; mt < 4; ++mt)
        #pragma unroll
        for (int nt = 0; nt < 2; ++nt)
            #pragma unroll
            for (int rr = 0; rr < 4; ++rr)
                sC[(mt * 16 + crow + rr) * LDC + nx + nt * 16 + lr] = acc[mt][nt][rr];
    __syncthreads();

    // ---- write 64x128 tile x 4 views: 16B nontemporal stores (output never re-read;
    // keep the 12.5MB input resident in L2). NMAX%4==0 -> no partial tails. ----
    const int rs = tid >> 5;     // 0..7
    const int cs = tid & 31;     // 4-float (16B) segment
    const int gc = j0 + cs * 4;
    #pragma unroll
    for (int it = 0; it < 8; ++it) {
        const int r  = it * 8 + rs;
        const int gr = i0 + r;
        if (gr >= NMAX || gc >= NMAX) continue;   // rows/cols 508..511 of last tiles
        const v4u v = *(const v4u*)&sC[r * LDC + cs * 4];
        const size_t rowbase = (size_t)gr * NMAX + gc;  // multiple of 4 -> 16B aligned
        #pragma unroll
        for (int vv = 0; vv < NV; ++vv) {
            const size_t o = (size_t)(b * NV + vv) * (size_t)(NMAX * NMAX) + rowbase;
            __builtin_nontemporal_store(v, (v4u*)(out + o));
        }
    }
}

extern "C" void kernel_launch(void* const* d_in, const int* in_sizes, int n_in,
                              void* d_out, int out_size, void* d_ws, size_t ws_size,
                              hipStream_t stream) {
    const float* z      = (const float*)d_in[0];
    const int*   counts = (const int*)d_in[1];
    float*       out    = (float*)d_out;
    // 64 graphs x 32 tiles (8x4 of 64x128 over 508 padded nodes) = 2048 blocks
    adj_gram_kernel<<<dim3(64 * 32), dim3(256), 0, stream>>>(z, counts, out);
}